// Round 2
// baseline (235.889 us; speedup 1.0000x reference)
//
#include <hip/hip_runtime.h>
#include <stdint.h>

// Problem constants (from reference)
#define N_NODES 16384
#define E_EDGES 524288
#define F_INF   128      // node feature dim
#define H_DIM   256      // hidden dim
#define A_DIM   64       // action size
#define WPR     (N_NODES / 32)   // bitmap words per row = 512

// ---------------- ws layout ----------------
// [0, 32MiB)        : dedupe bitmap, uint32[N_NODES][WPR]
// [32MiB, +1KiB)    : g_accum float[256]
// [32MiB+1KiB, ...) : t float[N_NODES][128]  (normalized aggregate)
#define BITMAP_BYTES ((size_t)N_NODES * WPR * 4)            // 33,554,432
#define GACC_OFF     BITMAP_BYTES
#define T_OFF        (BITMAP_BYTES + 1024)

// ---------------------------------------------------------------
// K1: scatter edges into dedupe bitmap. adj[src][dst] |= 1.
// ---------------------------------------------------------------
__global__ __launch_bounds__(256) void k_scatter(const int* __restrict__ ei,
                                                 uint32_t* __restrict__ bm) {
    int e = blockIdx.x * 256 + threadIdx.x;
    if (e < E_EDGES) {
        int s = ei[e];              // edge_index[0][e]
        int d = ei[E_EDGES + e];    // edge_index[1][e]
        atomicOr(&bm[(size_t)s * WPR + (d >> 5)], 1u << (d & 31));
    }
}

// ---------------------------------------------------------------
// K2: one wave per node. Scan bitmap row, gather X rows of unique
// neighbors (all 64 lanes cooperatively -> coalesced 256B loads),
// add self (eye), normalize by deg = popcount + 1, store t[n][:].
// Wave-uniform control flow: ballot/shfl broadcast each word.
// ---------------------------------------------------------------
__global__ __launch_bounds__(256) void k_gather(const float* __restrict__ X,
                                                const uint32_t* __restrict__ bm,
                                                float* __restrict__ t) {
    int n    = blockIdx.x * 4 + (threadIdx.x >> 6);   // node = wave id
    int lane = threadIdx.x & 63;
    const uint32_t* row = bm + (size_t)n * WPR;

    // identity term: X[n]
    float a0 = X[n * F_INF + lane];
    float a1 = X[n * F_INF + 64 + lane];
    int   cnt = 1;                                    // eye contributes 1 to deg

    for (int base = 0; base < WPR; base += 64) {
        uint32_t bits = row[base + lane];
        unsigned long long nz = __ballot(bits != 0u);
        while (nz) {
            int l = __builtin_ctzll(nz);
            nz &= nz - 1;
            uint32_t w = (uint32_t)__shfl((int)bits, l);   // wave-uniform word
            int dbase = (base + l) << 5;
            while (w) {
                int b = __builtin_ctz(w);
                w &= w - 1;
                int d = dbase + b;
                a0 += X[d * F_INF + lane];
                a1 += X[d * F_INF + 64 + lane];
                ++cnt;
            }
        }
    }
    float inv = 1.0f / (float)cnt;
    t[n * F_INF + lane]      = a0 * inv;
    t[n * F_INF + 64 + lane] = a1 * inv;
}

// ---------------------------------------------------------------
// K3: h[n] = relu(W_gnn @ t[n] + b_gnn); g_accum[j] += sum_n h[n][j].
// 256 threads/block, thread j owns output j; its W row lives in
// 128 VGPRs; t[n] broadcast via LDS float4 reads. 64 nodes/block.
// ---------------------------------------------------------------
#define NPB 64
__global__ __launch_bounds__(256) void k_gemm(const float* __restrict__ t,
                                              const float* __restrict__ Wg,
                                              const float* __restrict__ bg,
                                              float* __restrict__ g_accum) {
    __shared__ __align__(16) float tv[F_INF];
    int j = threadIdx.x;

    // W row j -> registers (one-time, 131KB/block from L2/L3)
    float4 w[32];
    const float4* wrow = (const float4*)(Wg + j * F_INF);
#pragma unroll
    for (int q = 0; q < 32; ++q) w[q] = wrow[q];

    float bj = bg[j];
    float gpart = 0.0f;
    int n0 = blockIdx.x * NPB;

    for (int n = 0; n < NPB; ++n) {
        __syncthreads();                       // protect tv from previous iter
        if (j < 32)
            ((float4*)tv)[j] = ((const float4*)(t + (size_t)(n0 + n) * F_INF))[j];
        __syncthreads();
        float acc = bj;
#pragma unroll
        for (int q = 0; q < 32; ++q) {
            float4 v = ((const float4*)tv)[q];   // LDS broadcast b128
            acc += w[q].x * v.x + w[q].y * v.y + w[q].z * v.z + w[q].w * v.w;
        }
        gpart += fmaxf(acc, 0.0f);
    }
    atomicAdd(&g_accum[j], gpart);
}

// ---------------------------------------------------------------
// K4: heads. g = g_accum/N; actor & critic MLPs; softmax; value.
// Single block of 256 threads.
// ---------------------------------------------------------------
__global__ __launch_bounds__(256) void k_heads(const float* __restrict__ g_accum,
                                               const float* __restrict__ W_a1,
                                               const float* __restrict__ b_a1,
                                               const float* __restrict__ W_a2,
                                               const float* __restrict__ b_a2,
                                               const float* __restrict__ W_c1,
                                               const float* __restrict__ b_c1,
                                               const float* __restrict__ W_c2,
                                               const float* __restrict__ b_c2,
                                               float* __restrict__ out) {
    __shared__ float gv[H_DIM];
    __shared__ float ah[128];   // actor hidden
    __shared__ float ch[128];   // critic hidden
    int tid = threadIdx.x;

    gv[tid] = g_accum[tid] * (1.0f / (float)N_NODES);
    __syncthreads();

    if (tid < 128) {
        float acc = b_a1[tid];
        const float* wr = W_a1 + tid * H_DIM;
        for (int k = 0; k < H_DIM; ++k) acc += wr[k] * gv[k];
        ah[tid] = fmaxf(acc, 0.0f);
    } else {
        int i = tid - 128;
        float acc = b_c1[i];
        const float* wr = W_c1 + i * H_DIM;
        for (int k = 0; k < H_DIM; ++k) acc += wr[k] * gv[k];
        ch[i] = fmaxf(acc, 0.0f);
    }
    __syncthreads();

    if (tid < 64) {
        // actor logits + wave softmax (lanes 0..63 of wave 0)
        float acc = b_a2[tid];
        const float* wr = W_a2 + tid * 128;
        for (int i = 0; i < 128; ++i) acc += wr[i] * ah[i];
        float m = acc;
        for (int off = 32; off; off >>= 1) m = fmaxf(m, __shfl_xor(m, off));
        float e = expf(acc - m);
        float s = e;
        for (int off = 32; off; off >>= 1) s += __shfl_xor(s, off);
        out[tid] = e / s;
    } else if (tid < 128) {
        // value on wave 1
        int l = tid - 64;
        float acc = 0.0f;
        for (int i = l; i < 128; i += 64) acc += W_c2[i] * ch[i];
        for (int off = 32; off; off >>= 1) acc += __shfl_xor(acc, off);
        if (l == 0) out[A_DIM] = acc + b_c2[0];
    }
}

// ---------------------------------------------------------------
extern "C" void kernel_launch(void* const* d_in, const int* in_sizes, int n_in,
                              void* d_out, int out_size, void* d_ws, size_t ws_size,
                              hipStream_t stream) {
    const float* X    = (const float*)d_in[0];
    const int*   ei   = (const int*)d_in[1];
    const float* Wg   = (const float*)d_in[2];
    const float* bg   = (const float*)d_in[3];
    const float* W_a1 = (const float*)d_in[4];
    const float* b_a1 = (const float*)d_in[5];
    const float* W_a2 = (const float*)d_in[6];
    const float* b_a2 = (const float*)d_in[7];
    const float* W_c1 = (const float*)d_in[8];
    const float* b_c1 = (const float*)d_in[9];
    const float* W_c2 = (const float*)d_in[10];
    const float* b_c2 = (const float*)d_in[11];
    float* out = (float*)d_out;

    uint8_t*  ws     = (uint8_t*)d_ws;
    uint32_t* bitmap = (uint32_t*)ws;
    float*    g_acc  = (float*)(ws + GACC_OFF);
    float*    t      = (float*)(ws + T_OFF);

    // zero bitmap + g_accum (ws is poisoned 0xAA before every launch)
    hipMemsetAsync(d_ws, 0, BITMAP_BYTES + 1024, stream);

    k_scatter<<<E_EDGES / 256, 256, 0, stream>>>(ei, bitmap);
    k_gather <<<N_NODES / 4, 256, 0, stream>>>(X, bitmap, t);
    k_gemm   <<<N_NODES / NPB, 256, 0, stream>>>(t, Wg, bg, g_acc);
    k_heads  <<<1, 256, 0, stream>>>(g_acc, W_a1, b_a1, W_a2, b_a2,
                                     W_c1, b_c1, W_c2, b_c2, out);
}